// Round 6
// baseline (588.580 us; speedup 1.0000x reference)
//
#include <hip/hip_runtime.h>
#include <hip/hip_bf16.h>
#include <stdint.h>

// ResNetV1 sparse conv block, MI355X (gfx950).
// out = relu( conv(relu(conv(x,W0)), W1) + x ),  conv[n,d] = sum_k sum_c x[idx[n,k],c] * W[k,c,d]
// N=150000, K=27, C=64.
// R6: traffic-reduction round. Model from R3/R5: time ~= FETCH / ~2.5 TB/s (random-gather
// L2-miss path saturated; concurrency/B-traffic/L2-delivery changes were all neutral).
//   - CHANNEL-SPLIT passes: loop s (channel half) OUTER, k INNER. Each pass's gather
//     touches only the 9.6 MB of 64-B lines of one 32-ch half (vs 19.2 MB) -> higher
//     per-XCD L2 hit rate -> lower FETCH.
//   - Non-temporal idx loads + output stores: stop evicting gather lines from L2.
//   - Otherwise identical to R5: rt=2 (32 rows/wave), barrier-free, LDS-free,
//     __launch_bounds__(64,4), no per-wave pipelining (R4 regression).

typedef __attribute__((ext_vector_type(8))) short short8;
typedef __attribute__((ext_vector_type(4))) float f32x4;

#define NV 150000
#define KOFF 27

static __device__ __forceinline__ ushort f2bf(float f) {
  union { float f; uint32_t u; } v; v.f = f;
  uint32_t u = v.u;
  return (ushort)((u + 0x7fffu + ((u >> 16) & 1u)) >> 16);
}

// Fused prep: x -> bf16 (4/thread), then pack W0, W1 into B-fragment order.
// Pack map: flat = (((k*2+s)*4+ct)*64 + l)*8 + j <- W[k][c=s*32+(l>>4)*8+j][d=ct*16+(l&15)]
__global__ void prep_kernel(const float* __restrict__ x,
                            const float* __restrict__ W0,
                            const float* __restrict__ W1,
                            ushort* __restrict__ xb,
                            ushort* __restrict__ wp0,
                            ushort* __restrict__ wp1,
                            int nc4, int wtot) {
  int i = blockIdx.x * 256 + threadIdx.x;
  if (i < nc4) {
    float4 v = ((const float4*)x)[i];
    ushort4 o;
    o.x = f2bf(v.x); o.y = f2bf(v.y); o.z = f2bf(v.z); o.w = f2bf(v.w);
    ((ushort4*)xb)[i] = o;
    return;
  }
  int o = i - nc4;
  const float* W = W0;
  ushort* wp = wp0;
  if (o >= wtot) { o -= wtot; W = W1; wp = wp1; }
  if (o >= wtot) return;
  int j  = o & 7;
  int l  = (o >> 3) & 63;
  int ct = (o >> 9) & 3;
  int s  = (o >> 11) & 1;
  int k  = o >> 12;
  int c  = s * 32 + (l >> 4) * 8 + j;
  int d  = ct * 16 + (l & 15);
  wp[o] = f2bf(W[(k * 64 + c) * 64 + d]);
}

// One wave (64 threads) per 32 rows (2 x 16-row MFMA tiles).
// MODE 0: relu(conv) -> bf16. MODE 1: relu(conv+resid) -> fp32.
template <int MODE>
__global__ __launch_bounds__(64, 4) void conv_kernel(
    const ushort* __restrict__ feat,   // [N,64] bf16 bits
    const int*    __restrict__ nbr,    // [N,27]
    const ushort* __restrict__ wp,     // packed W, 27*4096 bf16
    const float*  __restrict__ resid,  // [N,64] fp32 (MODE 1)
    ushort*       __restrict__ out_bf, // MODE 0
    float*        __restrict__ out_f,  // MODE 1
    int n) {
  const int lane = threadIdx.x;       // 0..63
  const int quad = lane >> 4;
  const int lo   = lane & 15;
  const int mw   = blockIdx.x * 32;

  int roff[2];
  #pragma unroll
  for (int rt = 0; rt < 2; ++rt) {
    int r = mw + rt * 16 + lo;
    r = r < n ? r : n - 1;
    roff[rt] = r * KOFF;
  }

  const short8* wv = (const short8*)wp;  // frag (s*4+ct) of offset k: wv[k*512 + (s*4+ct)*64 + lane]

  f32x4 acc[2][4];
  #pragma unroll
  for (int rt = 0; rt < 2; ++rt)
    #pragma unroll
    for (int ct = 0; ct < 4; ++ct)
      acc[rt][ct] = (f32x4)0.0f;

  // Channel-half passes: s=0 -> cols 0..31 (ct 0..1... NO: ct spans output cols; s spans
  // the K dimension half). acc[rt][ct] accumulates over both passes.
  #pragma unroll 1
  for (int s = 0; s < 2; ++s) {
    int gi[2];
    #pragma unroll
    for (int rt = 0; rt < 2; ++rt) gi[rt] = __builtin_nontemporal_load(&nbr[roff[rt]]);

    #pragma unroll 1
    for (int k = 0; k < KOFF; ++k) {
      // Gather A fragments for this channel half: ONE 16-B read per row tile.
      short8 a[2];
      #pragma unroll
      for (int rt = 0; rt < 2; ++rt)
        a[rt] = *(const short8*)(feat + gi[rt] * 64 + s * 32 + quad * 8);
      // Prefetch neighbor indices for k+1 (non-temporal: streamed, don't cache).
      if (k + 1 < KOFF) {
        #pragma unroll
        for (int rt = 0; rt < 2; ++rt) gi[rt] = __builtin_nontemporal_load(&nbr[roff[rt] + k + 1]);
      }
      // B fragments for (k, s): 4 x 1KB coalesced, L2-hot (216 KB total).
      short8 b[4];
      #pragma unroll
      for (int ct = 0; ct < 4; ++ct) b[ct] = wv[k * 512 + (s * 4 + ct) * 64 + lane];
      // 8 MFMAs.
      #pragma unroll
      for (int rt = 0; rt < 2; ++rt)
        #pragma unroll
        for (int ct = 0; ct < 4; ++ct)
          acc[rt][ct] = __builtin_amdgcn_mfma_f32_16x16x32_bf16(a[rt], b[ct], acc[rt][ct], 0, 0, 0);
    }
  }

  // Epilogue: acc[rt][ct][j] -> out[mw + rt*16 + quad*4 + j][ct*16 + lo]
  // Non-temporal stores: outputs are not re-read by this kernel; keep L2 for gathers.
  #pragma unroll
  for (int rt = 0; rt < 2; ++rt) {
    int rbase = mw + rt * 16 + quad * 4;
    #pragma unroll
    for (int ct = 0; ct < 4; ++ct) {
      int col = ct * 16 + lo;
      #pragma unroll
      for (int j = 0; j < 4; ++j) {
        int r = rbase + j;
        if (r < n) {
          float v = acc[rt][ct][j];
          if (MODE == 0) {
            v = v > 0.0f ? v : 0.0f;
            __builtin_nontemporal_store(f2bf(v), &out_bf[r * 64 + col]);
          } else {
            v += resid[r * 64 + col];
            v = v > 0.0f ? v : 0.0f;
            __builtin_nontemporal_store(v, &out_f[r * 64 + col]);
          }
        }
      }
    }
  }
}

extern "C" void kernel_launch(void* const* d_in, const int* in_sizes, int n_in,
                              void* d_out, int out_size, void* d_ws, size_t ws_size,
                              hipStream_t stream) {
  const float* x   = (const float*)d_in[0];
  const int*   nbr = (const int*)d_in[1];
  const float* W0  = (const float*)d_in[2];
  const float* W1  = (const float*)d_in[3];
  float* out = (float*)d_out;

  const int n    = NV;
  const int nc   = NV * 64;        // 9,600,000
  const int nc4  = nc / 4;         // 2,400,000
  const int wtot = KOFF * 4096;    // 110,592

  ushort* xb  = (ushort*)d_ws;
  ushort* yb  = xb + nc;
  ushort* wp0 = yb + nc;
  ushort* wp1 = wp0 + wtot;

  const int prep_units = nc4 + 2 * wtot;
  prep_kernel<<<(prep_units + 255) / 256, 256, 0, stream>>>(x, W0, W1, xb, wp0, wp1, nc4, wtot);

  const int grid = (n + 31) / 32;  // 4688 one-wave blocks
  conv_kernel<0><<<grid, 64, 0, stream>>>(xb, nbr, wp0, nullptr, yb, nullptr, n);
  conv_kernel<1><<<grid, 64, 0, stream>>>(yb, nbr, wp1, x, nullptr, out, n);
}

// Round 7
// 327.914 us; speedup vs baseline: 1.7949x; 1.7949x over previous
//
#include <hip/hip_runtime.h>
#include <hip/hip_bf16.h>
#include <stdint.h>

// ResNetV1 sparse conv block, MI355X (gfx950).
// out = relu( conv(relu(conv(x,W0)), W1) + x ),  conv[n,d] = sum_k sum_c x[idx[n,k],c] * W[k,c,d]
// N=150000, K=27, C=64.
// R7: R5 base (rt=2, 32 rows/wave, barrier-free, LDS-free, launch_bounds(64,4)) +
// register ping-pong gather pipeline (R4's ordering, now register-feasible at rt=2):
//   per phase: B-loads FIRST, then k+1 gathers, then MFMA -- the s_waitcnt for B (older)
//   leaves the younger gathers in flight across the MFMA block. idx prefetched 2 ahead.
// R6 lessons baked in: L2 fills at 128-B granularity (full row = one line-pair; never
// split the row across passes); no nontemporal hints (confounded regression).
// Model being tested: per-CU outstanding-miss concurrency is the limiter; deeper
// per-wave pipelining raises in-flight misses at constant occupancy.

typedef __attribute__((ext_vector_type(8))) short short8;
typedef __attribute__((ext_vector_type(4))) float f32x4;

#define NV 150000
#define KOFF 27

static __device__ __forceinline__ ushort f2bf(float f) {
  union { float f; uint32_t u; } v; v.f = f;
  uint32_t u = v.u;
  return (ushort)((u + 0x7fffu + ((u >> 16) & 1u)) >> 16);
}

// Fused prep: x -> bf16 (4/thread), then pack W0, W1 into B-fragment order.
// Pack map: flat = (((k*2+s)*4+ct)*64 + l)*8 + j <- W[k][c=s*32+(l>>4)*8+j][d=ct*16+(l&15)]
__global__ void prep_kernel(const float* __restrict__ x,
                            const float* __restrict__ W0,
                            const float* __restrict__ W1,
                            ushort* __restrict__ xb,
                            ushort* __restrict__ wp0,
                            ushort* __restrict__ wp1,
                            int nc4, int wtot) {
  int i = blockIdx.x * 256 + threadIdx.x;
  if (i < nc4) {
    float4 v = ((const float4*)x)[i];
    ushort4 o;
    o.x = f2bf(v.x); o.y = f2bf(v.y); o.z = f2bf(v.z); o.w = f2bf(v.w);
    ((ushort4*)xb)[i] = o;
    return;
  }
  int o = i - nc4;
  const float* W = W0;
  ushort* wp = wp0;
  if (o >= wtot) { o -= wtot; W = W1; wp = wp1; }
  if (o >= wtot) return;
  int j  = o & 7;
  int l  = (o >> 3) & 63;
  int ct = (o >> 9) & 3;
  int s  = (o >> 11) & 1;
  int k  = o >> 12;
  int c  = s * 32 + (l >> 4) * 8 + j;
  int d  = ct * 16 + (l & 15);
  wp[o] = f2bf(W[(k * 64 + c) * 64 + d]);
}

// One wave (64 threads) per 32 rows (2 x 16-row MFMA tiles).
// MODE 0: relu(conv) -> bf16. MODE 1: relu(conv+resid) -> fp32.
template <int MODE>
__global__ __launch_bounds__(64, 4) void conv_kernel(
    const ushort* __restrict__ feat,   // [N,64] bf16 bits
    const int*    __restrict__ nbr,    // [N,27]
    const ushort* __restrict__ wp,     // packed W, 27*4096 bf16
    const float*  __restrict__ resid,  // [N,64] fp32 (MODE 1)
    ushort*       __restrict__ out_bf, // MODE 0
    float*        __restrict__ out_f,  // MODE 1
    int n) {
  const int lane = threadIdx.x;       // 0..63
  const int quad = lane >> 4;
  const int lo   = lane & 15;
  const int mw   = blockIdx.x * 32;

  int roff[2];
  #pragma unroll
  for (int rt = 0; rt < 2; ++rt) {
    int r = mw + rt * 16 + lo;
    r = r < n ? r : n - 1;
    roff[rt] = r * KOFF;
  }

  const short8* wv = (const short8*)wp;  // frag t of offset k: wv[k*512 + t*64 + lane]

  f32x4 acc[2][4];
  #pragma unroll
  for (int rt = 0; rt < 2; ++rt)
    #pragma unroll
    for (int ct = 0; ct < 4; ++ct)
      acc[rt][ct] = (f32x4)0.0f;

  short8 aP[2][2], aQ[2][2];
  int giA[2], giB[2];

  // Prologue: idx k=0 -> gather aP(k=0); prefetch idx k=1.
  #pragma unroll
  for (int rt = 0; rt < 2; ++rt) giA[rt] = nbr[roff[rt]];
  #pragma unroll
  for (int rt = 0; rt < 2; ++rt) {
    const ushort* rowp = feat + giA[rt] * 64 + quad * 8;
    aP[rt][0] = *(const short8*)(rowp);
    aP[rt][1] = *(const short8*)(rowp + 32);
  }
  #pragma unroll
  for (int rt = 0; rt < 2; ++rt) giB[rt] = nbr[roff[rt] + 1];

  // 13 pairs handle k=0..25; tail handles k=26.
  #pragma unroll 1
  for (int k = 0; k < 26; k += 2) {
    // ---- even phase: consume aP(k); gather aQ(k+1) via giB; prefetch giA(k+2) ----
    {
      short8 b[8];
      #pragma unroll
      for (int t = 0; t < 8; ++t) b[t] = wv[k * 512 + t * 64 + lane];   // oldest
      #pragma unroll
      for (int rt = 0; rt < 2; ++rt) {
        const ushort* rowp = feat + giB[rt] * 64 + quad * 8;
        aQ[rt][0] = *(const short8*)(rowp);
        aQ[rt][1] = *(const short8*)(rowp + 32);
      }
      #pragma unroll
      for (int rt = 0; rt < 2; ++rt) giA[rt] = nbr[roff[rt] + k + 2];   // youngest
      #pragma unroll
      for (int s = 0; s < 2; ++s)
        #pragma unroll
        for (int rt = 0; rt < 2; ++rt)
          #pragma unroll
          for (int ct = 0; ct < 4; ++ct)
            acc[rt][ct] = __builtin_amdgcn_mfma_f32_16x16x32_bf16(aP[rt][s], b[s * 4 + ct], acc[rt][ct], 0, 0, 0);
    }
    // ---- odd phase: consume aQ(k+1); gather aP(k+2) via giA; prefetch giB(k+3) ----
    {
      short8 b[8];
      #pragma unroll
      for (int t = 0; t < 8; ++t) b[t] = wv[(k + 1) * 512 + t * 64 + lane];
      #pragma unroll
      for (int rt = 0; rt < 2; ++rt) {
        const ushort* rowp = feat + giA[rt] * 64 + quad * 8;
        aP[rt][0] = *(const short8*)(rowp);
        aP[rt][1] = *(const short8*)(rowp + 32);
      }
      if (k + 3 < KOFF) {
        #pragma unroll
        for (int rt = 0; rt < 2; ++rt) giB[rt] = nbr[roff[rt] + k + 3];
      }
      #pragma unroll
      for (int s = 0; s < 2; ++s)
        #pragma unroll
        for (int rt = 0; rt < 2; ++rt)
          #pragma unroll
          for (int ct = 0; ct < 4; ++ct)
            acc[rt][ct] = __builtin_amdgcn_mfma_f32_16x16x32_bf16(aQ[rt][s], b[s * 4 + ct], acc[rt][ct], 0, 0, 0);
    }
  }
  // ---- tail: k=26 consumes aP ----
  {
    short8 b[8];
    #pragma unroll
    for (int t = 0; t < 8; ++t) b[t] = wv[26 * 512 + t * 64 + lane];
    #pragma unroll
    for (int s = 0; s < 2; ++s)
      #pragma unroll
      for (int rt = 0; rt < 2; ++rt)
        #pragma unroll
        for (int ct = 0; ct < 4; ++ct)
          acc[rt][ct] = __builtin_amdgcn_mfma_f32_16x16x32_bf16(aP[rt][s], b[s * 4 + ct], acc[rt][ct], 0, 0, 0);
  }

  // Epilogue: acc[rt][ct][j] -> out[mw + rt*16 + quad*4 + j][ct*16 + lo]
  #pragma unroll
  for (int rt = 0; rt < 2; ++rt) {
    int rbase = mw + rt * 16 + quad * 4;
    #pragma unroll
    for (int ct = 0; ct < 4; ++ct) {
      int col = ct * 16 + lo;
      #pragma unroll
      for (int j = 0; j < 4; ++j) {
        int r = rbase + j;
        if (r < n) {
          float v = acc[rt][ct][j];
          if (MODE == 0) {
            v = v > 0.0f ? v : 0.0f;
            out_bf[r * 64 + col] = f2bf(v);
          } else {
            v += resid[r * 64 + col];
            v = v > 0.0f ? v : 0.0f;
            out_f[r * 64 + col] = v;
          }
        }
      }
    }
  }
}

extern "C" void kernel_launch(void* const* d_in, const int* in_sizes, int n_in,
                              void* d_out, int out_size, void* d_ws, size_t ws_size,
                              hipStream_t stream) {
  const float* x   = (const float*)d_in[0];
  const int*   nbr = (const int*)d_in[1];
  const float* W0  = (const float*)d_in[2];
  const float* W1  = (const float*)d_in[3];
  float* out = (float*)d_out;

  const int n    = NV;
  const int nc   = NV * 64;        // 9,600,000
  const int nc4  = nc / 4;         // 2,400,000
  const int wtot = KOFF * 4096;    // 110,592

  ushort* xb  = (ushort*)d_ws;
  ushort* yb  = xb + nc;
  ushort* wp0 = yb + nc;
  ushort* wp1 = wp0 + wtot;

  const int prep_units = nc4 + 2 * wtot;
  prep_kernel<<<(prep_units + 255) / 256, 256, 0, stream>>>(x, W0, W1, xb, wp0, wp1, nc4, wtot);

  const int grid = (n + 31) / 32;  // 4688 one-wave blocks
  conv_kernel<0><<<grid, 64, 0, stream>>>(xb, nbr, wp0, nullptr, yb, nullptr, n);
  conv_kernel<1><<<grid, 64, 0, stream>>>(yb, nbr, wp1, x, nullptr, out, n);
}

// Round 8
// 297.218 us; speedup vs baseline: 1.9803x; 1.1033x over previous
//
#include <hip/hip_runtime.h>
#include <hip/hip_bf16.h>
#include <stdint.h>

// ResNetV1 sparse conv block, MI355X (gfx950).
// out = relu( conv(relu(conv(x,W0)), W1) + x ),  conv[n,d] = sum_k sum_c x[idx[n,k],c] * W[k,c,d]
// N=150000, K=27, C=64.
// R8 = R5 (best: 124 us/conv) + wave-private LDS idx staging.
// Evidence so far: 5 structurally different kernels pin the conv at 124-129 us; random
// row-touch service rate is ~13.5/cycle chip-wide regardless of touch size, occupancy,
// pipelining, or B-traffic. This round removes the last NON-gather global request stream
// (strided idx reads, ~30 line-req/iter): whole 32x27 idx block (3456 B contiguous) is
// loaded once via coalesced int4 and served per-k from LDS (conflict-free ds_read).
// Decisive A/B: win => L2-request-rate model; neutral => pure random-touch wall (roofline).

typedef __attribute__((ext_vector_type(8))) short short8;
typedef __attribute__((ext_vector_type(4))) float f32x4;

#define NV 150000
#define KOFF 27

static __device__ __forceinline__ ushort f2bf(float f) {
  union { float f; uint32_t u; } v; v.f = f;
  uint32_t u = v.u;
  return (ushort)((u + 0x7fffu + ((u >> 16) & 1u)) >> 16);
}

// Fused prep: x -> bf16 (4/thread), then pack W0, W1 into B-fragment order.
// Pack map: flat = (((k*2+s)*4+ct)*64 + l)*8 + j <- W[k][c=s*32+(l>>4)*8+j][d=ct*16+(l&15)]
__global__ void prep_kernel(const float* __restrict__ x,
                            const float* __restrict__ W0,
                            const float* __restrict__ W1,
                            ushort* __restrict__ xb,
                            ushort* __restrict__ wp0,
                            ushort* __restrict__ wp1,
                            int nc4, int wtot) {
  int i = blockIdx.x * 256 + threadIdx.x;
  if (i < nc4) {
    float4 v = ((const float4*)x)[i];
    ushort4 o;
    o.x = f2bf(v.x); o.y = f2bf(v.y); o.z = f2bf(v.z); o.w = f2bf(v.w);
    ((ushort4*)xb)[i] = o;
    return;
  }
  int o = i - nc4;
  const float* W = W0;
  ushort* wp = wp0;
  if (o >= wtot) { o -= wtot; W = W1; wp = wp1; }
  if (o >= wtot) return;
  int j  = o & 7;
  int l  = (o >> 3) & 63;
  int ct = (o >> 9) & 3;
  int s  = (o >> 11) & 1;
  int k  = o >> 12;
  int c  = s * 32 + (l >> 4) * 8 + j;
  int d  = ct * 16 + (l & 15);
  wp[o] = f2bf(W[(k * 64 + c) * 64 + d]);
}

// One wave (64 threads) per 32 rows (2 x 16-row MFMA tiles).
// MODE 0: relu(conv) -> bf16. MODE 1: relu(conv+resid) -> fp32.
template <int MODE>
__global__ __launch_bounds__(64, 4) void conv_kernel(
    const ushort* __restrict__ feat,   // [N,64] bf16 bits
    const int*    __restrict__ nbr,    // [N,27]
    const ushort* __restrict__ wp,     // packed W, 27*4096 bf16
    const float*  __restrict__ resid,  // [N,64] fp32 (MODE 1)
    ushort*       __restrict__ out_bf, // MODE 0
    float*        __restrict__ out_f,  // MODE 1
    int n) {
  __shared__ int sIdx[864];            // 32 rows x 27 offsets, wave-private

  const int lane = threadIdx.x;       // 0..63
  const int quad = lane >> 4;
  const int lo   = lane & 15;
  const int mw   = blockIdx.x * 32;

  // ---- Stage this wave's idx block: nbr[mw*27 .. (mw+32)*27), 864 ints, coalesced int4.
  {
    const int total = n * KOFF;
    const int g0    = mw * KOFF;      // int offset; byte offset = blockIdx*3456, 16-B aligned
    #pragma unroll
    for (int u = 0; u < 3; ++u) {
      int j  = lane + 64 * u;         // int4 index within block (0..191)
      int ai = g0 + 4 * j;
      ai = ai + 4 <= total ? ai : (total - 4);   // clamp address (tail block only)
      int4 v = *(const int4*)(nbr + ai);
      ((int4*)sIdx)[j] = v;
    }
    if (lane < 24) {                  // int4 indices 192..215
      int j  = 192 + lane;
      int ai = g0 + 4 * j;
      ai = ai + 4 <= total ? ai : (total - 4);
      int4 v = *(const int4*)(nbr + ai);
      ((int4*)sIdx)[j] = v;
    }
  }
  __syncthreads();  // single wave: compiles to lgkm drain + cheap barrier

  // Per-lane LDS offsets for the 2 row tiles (row = rt*16+lo within the block).
  int ioff[2];
  #pragma unroll
  for (int rt = 0; rt < 2; ++rt) ioff[rt] = (rt * 16 + lo) * KOFF;

  const short8* wv = (const short8*)wp;  // frag t of offset k: wv[k*512 + t*64 + lane]

  f32x4 acc[2][4];
  #pragma unroll
  for (int rt = 0; rt < 2; ++rt)
    #pragma unroll
    for (int ct = 0; ct < 4; ++ct)
      acc[rt][ct] = (f32x4)0.0f;

  int gi[2];
  #pragma unroll
  for (int rt = 0; rt < 2; ++rt) {
    int g = sIdx[ioff[rt]];
    gi[rt] = g < n ? g : 0;           // clamped-tail safety
  }

  #pragma unroll 1
  for (int k = 0; k < KOFF; ++k) {
    // Gather A fragments (random rows -> long latency; issue first).
    short8 a[2][2];
    #pragma unroll
    for (int rt = 0; rt < 2; ++rt) {
      const ushort* rowp = feat + gi[rt] * 64 + quad * 8;
      a[rt][0] = *(const short8*)(rowp);
      a[rt][1] = *(const short8*)(rowp + 32);
    }
    // Next-k idx from LDS (conflict-free: 27*lo mod 32 all-distinct; same-lo broadcast).
    if (k + 1 < KOFF) {
      #pragma unroll
      for (int rt = 0; rt < 2; ++rt) gi[rt] = sIdx[ioff[rt] + k + 1];
    }
    // B fragments (1 KB/instr coalesced, L1/L2-hot: 8 KB/k shared by all waves).
    short8 b[8];
    #pragma unroll
    for (int t = 0; t < 8; ++t) b[t] = wv[k * 512 + t * 64 + lane];
    // 16 MFMAs.
    #pragma unroll
    for (int s = 0; s < 2; ++s)
      #pragma unroll
      for (int rt = 0; rt < 2; ++rt)
        #pragma unroll
        for (int ct = 0; ct < 4; ++ct)
          acc[rt][ct] = __builtin_amdgcn_mfma_f32_16x16x32_bf16(a[rt][s], b[s * 4 + ct], acc[rt][ct], 0, 0, 0);
  }

  // Epilogue: acc[rt][ct][j] -> out[mw + rt*16 + quad*4 + j][ct*16 + lo]
  #pragma unroll
  for (int rt = 0; rt < 2; ++rt) {
    int rbase = mw + rt * 16 + quad * 4;
    #pragma unroll
    for (int ct = 0; ct < 4; ++ct) {
      int col = ct * 16 + lo;
      #pragma unroll
      for (int j = 0; j < 4; ++j) {
        int r = rbase + j;
        if (r < n) {
          float v = acc[rt][ct][j];
          if (MODE == 0) {
            v = v > 0.0f ? v : 0.0f;
            out_bf[r * 64 + col] = f2bf(v);
          } else {
            v += resid[r * 64 + col];
            v = v > 0.0f ? v : 0.0f;
            out_f[r * 64 + col] = v;
          }
        }
      }
    }
  }
}

extern "C" void kernel_launch(void* const* d_in, const int* in_sizes, int n_in,
                              void* d_out, int out_size, void* d_ws, size_t ws_size,
                              hipStream_t stream) {
  const float* x   = (const float*)d_in[0];
  const int*   nbr = (const int*)d_in[1];
  const float* W0  = (const float*)d_in[2];
  const float* W1  = (const float*)d_in[3];
  float* out = (float*)d_out;

  const int n    = NV;
  const int nc   = NV * 64;        // 9,600,000
  const int nc4  = nc / 4;         // 2,400,000
  const int wtot = KOFF * 4096;    // 110,592

  ushort* xb  = (ushort*)d_ws;
  ushort* yb  = xb + nc;
  ushort* wp0 = yb + nc;
  ushort* wp1 = wp0 + wtot;

  const int prep_units = nc4 + 2 * wtot;
  prep_kernel<<<(prep_units + 255) / 256, 256, 0, stream>>>(x, W0, W1, xb, wp0, wp1, nc4, wtot);

  const int grid = (n + 31) / 32;  // 4688 one-wave blocks
  conv_kernel<0><<<grid, 64, 0, stream>>>(xb, nbr, wp0, nullptr, yb, nullptr, n);
  conv_kernel<1><<<grid, 64, 0, stream>>>(yb, nbr, wp1, x, nullptr, out, n);
}